// Round 4
// baseline (859.214 us; speedup 1.0000x reference)
//
#include <hip/hip_runtime.h>
#include <cmath>

// ---- TwinsBlock: B=32, H=W=56, C=256, heads=8, ws=7. fp32 I/O, bf16 MFMA ----
typedef __bf16 bf16;
typedef __bf16 bf16x4 __attribute__((ext_vector_type(4)));
typedef __bf16 bf16x8 __attribute__((ext_vector_type(8)));
typedef float floatx4 __attribute__((ext_vector_type(4)));

constexpr int BATCH = 32;
constexpr int NTOK  = 3136;            // 56*56
constexpr int CDIM  = 256;
constexpr int MROWS = BATCH * NTOK;    // 100352
constexpr int HIDD  = 1024;
constexpr float ATTN_SCALE = 0.17677669529663689f;  // 32^-0.5

// cheap branchless GELU (tanh form), max abs err vs exact ~3e-3
__device__ __forceinline__ float gelu_fast(float x) {
    float z = 0.79788456080286536f * x + 0.03567740813636141f * (x * x * x);
    float a = fabsf(z);
    float e = __expf(-2.0f * a);
    float t = 1.0f - 2.0f * e / (1.0f + e);     // tanh(|z|), e<=1 so no overflow/NaN
    t = copysignf(t, z);
    return 0.5f * x * (1.0f + t);
}

__device__ __forceinline__ void load8(const bf16* p, float* o) {
    bf16x8 v = *reinterpret_cast<const bf16x8*>(p);
#pragma unroll
    for (int j = 0; j < 8; j++) o[j] = (float)v[j];
}

// async global->LDS, 16B per lane, wave-uniform LDS base + lane*16
__device__ __forceinline__ void gload_lds16(const void* g, void* l) {
    __builtin_amdgcn_global_load_lds(
        (const __attribute__((address_space(1))) void*)g,
        (__attribute__((address_space(3))) void*)l, 16, 0, 0);
}

// ---------------- weight convert + transpose: fp32 [K,N] -> bf16 [N,K] ----------------
__global__ __launch_bounds__(256) void wt_kernel(
    const float* __restrict__ Win, bf16* __restrict__ Wt, int Ksz, int Nsz)
{
    int id = blockIdx.x * 256 + threadIdx.x;       // over N*K, write-coalesced
    int n = id / Ksz, k = id % Ksz;
    Wt[id] = (bf16)Win[(size_t)k * Nsz + n];
}

// ---- fc2 weight fold: Wt[n,k]=bf16(g[k]W[k,n]); c1[n]=sum g W; c2[n]=sum b W + bias[n] ----
__global__ __launch_bounds__(256) void wt_fold_kernel(
    const float* __restrict__ W, const float* __restrict__ g, const float* __restrict__ b,
    const float* __restrict__ bias, bf16* __restrict__ Wt,
    float* __restrict__ c1, float* __restrict__ c2)
{
    int n    = (blockIdx.x * 256 + threadIdx.x) >> 6;   // one wave per output col n (0..255)
    int lane = threadIdx.x & 63;
    float s1 = 0.f, s2 = 0.f;
    for (int k = lane; k < HIDD; k += 64) {
        float wkn = W[(size_t)k * CDIM + n];
        float gw  = g[k] * wkn;
        s1 += gw;
        s2 += b[k] * wkn;
        Wt[(size_t)n * HIDD + k] = (bf16)gw;
    }
#pragma unroll
    for (int off = 32; off > 0; off >>= 1) {
        s1 += __shfl_xor(s1, off, 64);
        s2 += __shfl_xor(s2, off, 64);
    }
    if (lane == 0) { c1[n] = s1; c2[n] = s2 + bias[n]; }
}

// ---------------- fused LN (stats+apply): fp32 [M,256] -> bf16 [M,256] ----------------
__global__ __launch_bounds__(256) void ln_apply_f32_kernel(
    const float* __restrict__ X, const float* __restrict__ g,
    const float* __restrict__ b, bf16* __restrict__ Y)
{
    int tok  = (blockIdx.x * 256 + threadIdx.x) >> 6;   // one wave per token
    int lane = threadIdx.x & 63;
    const float* row = X + (size_t)tok * CDIM;
    float4 v = *reinterpret_cast<const float4*>(row + lane * 4);
    float s  = v.x + v.y + v.z + v.w;
    float ss = v.x * v.x + v.y * v.y + v.z * v.z + v.w * v.w;
#pragma unroll
    for (int off = 32; off > 0; off >>= 1) {
        s  += __shfl_xor(s,  off, 64);
        ss += __shfl_xor(ss, off, 64);
    }
    float mean = s * (1.0f / CDIM);
    float var  = ss * (1.0f / CDIM) - mean * mean;
    if (var < 0.f) var = 0.f;
    float rstd = rsqrtf(var + 1e-5f);
    float4 gg = *reinterpret_cast<const float4*>(g + lane * 4);
    float4 bb = *reinterpret_cast<const float4*>(b + lane * 4);
    bf16x4 o;
    o[0] = (bf16)((v.x - mean) * rstd * gg.x + bb.x);
    o[1] = (bf16)((v.y - mean) * rstd * gg.y + bb.y);
    o[2] = (bf16)((v.z - mean) * rstd * gg.z + bb.z);
    o[3] = (bf16)((v.w - mean) * rstd * gg.w + bb.w);
    *reinterpret_cast<bf16x4*>(Y + (size_t)tok * CDIM + lane * 4) = o;
}

// ---- finalize mlp-LN stats: (s,ss) -> (rstd, -rstd*mean) ----
__global__ __launch_bounds__(256) void finalize_stats_kernel(float2* __restrict__ st)
{
    int i = blockIdx.x * 256 + threadIdx.x;
    float2 v = st[i];
    float m   = v.x * (1.0f / HIDD);
    float var = v.y * (1.0f / HIDD) - m * m;
    if (var < 0.f) var = 0.f;
    float r = rsqrtf(var + 1e-5f);
    st[i] = make_float2(r, -r * m);
}

// ---------------- m97-style GEMM: 128x128 tile, BK=64, 4 waves, 4x4 16x16x32 MFMA ----
// EPI 0: out bf16 = acc + bias                      (LDS-staged coalesced store)
// EPI 1: out bf16 = gelu(acc + bias), + row stats atomics (LDS-staged store)
// EPI 2: out fp32 = st.x*acc + st.y*c1[col] + c2[col] + resid   (mlp-LN folded)
template<int EPI>
__global__ __launch_bounds__(256) void gemm_bt_kernel(
    const bf16* __restrict__ A, const bf16* __restrict__ Bt,
    const float* __restrict__ bias, const float* __restrict__ resid,
    const float* __restrict__ c1, const float* __restrict__ c2,
    const float2* __restrict__ stats_in, float* __restrict__ stats_out,
    void* __restrict__ outv, int Nsz, int Ksz)
{
    __shared__ char smem[34816];                 // K-loop: lA|lB (32KB); epilogue: bf16 tile 128x136
    bf16* lA = (bf16*)smem;                      // [128][64]
    bf16* lB = (bf16*)(smem + 128 * 64 * 2);     // [128][64]
    const int t = threadIdx.x;
    const int lane = t & 63, w = t >> 6;
    const int quad = lane >> 4, l16 = lane & 15;
    const int wm = (w >> 1) * 64, wn = (w & 1) * 64;
    const size_t m0 = (size_t)blockIdx.y * 128;
    const int n0 = blockIdx.x * 128;
    const int srow = w * 32 + (lane >> 3);
    const int scol = (lane & 7) * 8;

    floatx4 acc[4][4] = {};

    for (int kc = 0; kc < Ksz; kc += 64) {
#pragma unroll
        for (int j = 0; j < 4; j++) {
            gload_lds16(A  + (m0 + srow + j * 8) * Ksz + kc + scol, &lA[(w * 32 + j * 8) * 64]);
            gload_lds16(Bt + (size_t)(n0 + srow + j * 8) * Ksz + kc + scol, &lB[(w * 32 + j * 8) * 64]);
        }
        __syncthreads();
#pragma unroll
        for (int ks = 0; ks < 64; ks += 32) {
            bf16x8 af[4], bfv[4];
#pragma unroll
            for (int i = 0; i < 4; i++) {
                af[i]  = *reinterpret_cast<const bf16x8*>(&lA[(wm + i * 16 + l16) * 64 + ks + quad * 8]);
                bfv[i] = *reinterpret_cast<const bf16x8*>(&lB[(wn + i * 16 + l16) * 64 + ks + quad * 8]);
            }
#pragma unroll
            for (int mi = 0; mi < 4; mi++)
#pragma unroll
                for (int ni = 0; ni < 4; ni++)
                    acc[mi][ni] = __builtin_amdgcn_mfma_f32_16x16x32_bf16(af[mi], bfv[ni], acc[mi][ni], 0, 0, 0);
        }
        __syncthreads();
    }

    if (EPI == 2) {
        // fp32 direct store with folded mlp-LN + residual (K=1024 amortizes this)
#pragma unroll
        for (int ni = 0; ni < 4; ni++) {
            int col = n0 + wn + ni * 16 + l16;
            float cc1 = c1[col], cc2 = c2[col];
#pragma unroll
            for (int mi = 0; mi < 4; mi++) {
#pragma unroll
                for (int r = 0; r < 4; r++) {
                    size_t row = m0 + wm + mi * 16 + quad * 4 + r;
                    float2 st = stats_in[row];
                    float v = st.x * acc[mi][ni][r] + st.y * cc1 + cc2 + resid[row * Nsz + col];
                    ((float*)outv)[row * Nsz + col] = v;
                }
            }
        }
    } else {
        bf16* ctile = (bf16*)smem;               // [128][136]
        float bcol[4];
#pragma unroll
        for (int ni = 0; ni < 4; ni++) bcol[ni] = bias[n0 + wn + ni * 16 + l16];
#pragma unroll
        for (int mi = 0; mi < 4; mi++) {
#pragma unroll
            for (int r = 0; r < 4; r++) {
                int lrow = wm + mi * 16 + quad * 4 + r;
                float s = 0.f, ss = 0.f;
#pragma unroll
                for (int ni = 0; ni < 4; ni++) {
                    float v = acc[mi][ni][r] + bcol[ni];
                    if (EPI == 1) v = gelu_fast(v);
                    bf16 bv = (bf16)v;
                    if (EPI == 1) { float vr = (float)bv; s += vr; ss += vr * vr; }
                    ctile[lrow * 136 + wn + ni * 16 + l16] = bv;
                }
                if (EPI == 1) {
#pragma unroll
                    for (int off = 1; off < 16; off <<= 1) {
                        s  += __shfl_xor(s,  off, 64);
                        ss += __shfl_xor(ss, off, 64);
                    }
                    if (l16 == 0) {
                        atomicAdd(&stats_out[(m0 + lrow) * 2],     s);
                        atomicAdd(&stats_out[(m0 + lrow) * 2 + 1], ss);
                    }
                }
            }
        }
        __syncthreads();
        bf16* out = (bf16*)outv;
#pragma unroll
        for (int it = 0; it < 8; it++) {
            int row = it * 16 + (t >> 4);
            int col = (t & 15) * 8;
            bf16x8 vv = *reinterpret_cast<const bf16x8*>(&ctile[row * 136 + col]);
            *reinterpret_cast<bf16x8*>(out + (m0 + row) * Nsz + n0 + col) = vv;
        }
    }
}

// ---------------- windowed attention, one wave = one (batch, window, head) ----------------
__global__ __launch_bounds__(256) void attn_kernel(
    const bf16* __restrict__ qkv, const float* __restrict__ X,
    float* __restrict__ x1)
{
    __shared__ bf16 pbuf[4][64 * 72];   // P[i][j], per wave
    __shared__ bf16 vtbuf[4][32 * 72];  // V^T[d][j], per wave
    const int w = threadIdx.x >> 6, lane = threadIdx.x & 63;
    const int quad = lane >> 4, l16 = lane & 15;
    const int blk = blockIdx.x;
    const int hg = blk & 1, p = (blk >> 1) & 63, b = blk >> 7;
    const int h = hg * 4 + w;
    const int py = p >> 3, px = p & 7;
    const size_t gbase = (size_t)b * NTOK + py * 7 * 56 + px * 7;
    bf16* P  = pbuf[w];
    bf16* VT = vtbuf[w];

    unsigned int* vz = (unsigned int*)VT;
    for (int i = lane; i < 32 * 72 / 2; i += 64) vz[i] = 0u;

    for (int idx = lane; idx < 49 * 4; idx += 64) {
        int tk = idx >> 2, d8 = (idx & 3) * 8;
        size_t g = gbase + (tk / 7) * 56 + (tk % 7);
        bf16x8 vv = *reinterpret_cast<const bf16x8*>(qkv + g * 768 + 512 + h * 32 + d8);
#pragma unroll
        for (int j = 0; j < 8; j++) VT[(d8 + j) * 72 + tk] = vv[j];
    }

    bf16x8 qf[4], kf[4];
#pragma unroll
    for (int mt = 0; mt < 4; mt++) {
        int i = mt * 16 + l16; if (i > 48) i = 48;   // clamp pad rows -> finite dups
        size_t g = gbase + (i / 7) * 56 + (i % 7);
        qf[mt] = *reinterpret_cast<const bf16x8*>(qkv + g * 768 +       h * 32 + quad * 8);
        kf[mt] = *reinterpret_cast<const bf16x8*>(qkv + g * 768 + 256 + h * 32 + quad * 8);
    }

    floatx4 s[4][4];
#pragma unroll
    for (int mt = 0; mt < 4; mt++)
#pragma unroll
        for (int nt = 0; nt < 4; nt++) {
            floatx4 z = {};
            s[mt][nt] = __builtin_amdgcn_mfma_f32_16x16x32_bf16(qf[mt], kf[nt], z, 0, 0, 0);
        }

#pragma unroll
    for (int mt = 0; mt < 4; mt++) {
#pragma unroll
        for (int r = 0; r < 4; r++) {
            float mx = -1e30f;
#pragma unroll
            for (int nt = 0; nt < 4; nt++) {
                int col = nt * 16 + l16;
                float v = (col < 49) ? s[mt][nt][r] * ATTN_SCALE : -1e30f;
                s[mt][nt][r] = v;
                mx = fmaxf(mx, v);
            }
#pragma unroll
            for (int off = 1; off < 16; off <<= 1) mx = fmaxf(mx, __shfl_xor(mx, off, 64));
            float sum = 0.f;
#pragma unroll
            for (int nt = 0; nt < 4; nt++) {
                float e = __expf(s[mt][nt][r] - mx);
                s[mt][nt][r] = e;
                sum += e;
            }
#pragma unroll
            for (int off = 1; off < 16; off <<= 1) sum += __shfl_xor(sum, off, 64);
            float inv = 1.0f / sum;
            int prow = mt * 16 + quad * 4 + r;
#pragma unroll
            for (int nt = 0; nt < 4; nt++)
                P[prow * 72 + nt * 16 + l16] = (bf16)(s[mt][nt][r] * inv);
        }
    }

    __syncthreads();

    floatx4 o[4][2] = {};
#pragma unroll
    for (int ks = 0; ks < 2; ks++) {
        bf16x8 pf[4], vf[2];
#pragma unroll
        for (int mt = 0; mt < 4; mt++)
            pf[mt] = *reinterpret_cast<const bf16x8*>(&P[(mt * 16 + l16) * 72 + ks * 32 + quad * 8]);
#pragma unroll
        for (int nt = 0; nt < 2; nt++)
            vf[nt] = *reinterpret_cast<const bf16x8*>(&VT[(nt * 16 + l16) * 72 + ks * 32 + quad * 8]);
#pragma unroll
        for (int mt = 0; mt < 4; mt++)
#pragma unroll
            for (int nt = 0; nt < 2; nt++)
                o[mt][nt] = __builtin_amdgcn_mfma_f32_16x16x32_bf16(pf[mt], vf[nt], o[mt][nt], 0, 0, 0);
    }

#pragma unroll
    for (int mt = 0; mt < 4; mt++) {
#pragma unroll
        for (int r = 0; r < 4; r++) {
            int i = mt * 16 + quad * 4 + r;
            if (i < 49) {
                size_t g = gbase + (i / 7) * 56 + (i % 7);
#pragma unroll
                for (int nt = 0; nt < 2; nt++) {
                    size_t adr = g * CDIM + h * 32 + nt * 16 + l16;
                    x1[adr] = X[adr] + o[mt][nt][r];
                }
            }
        }
    }
}

// ---------------- launcher ----------------
// ws: qkv_wt 0.38MB | fc1_wt 0.5MB | fc2_wt 0.5MB | c1 1KB | c2 1KB | stats3 0.8MB |
//     xn 51.4MB | union(qkvb 154MB, hbuf 205.5MB)  ~= 259.1 MB
extern "C" void kernel_launch(void* const* d_in, const int* in_sizes, int n_in,
                              void* d_out, int out_size, void* d_ws, size_t ws_size,
                              hipStream_t stream) {
    const float* x      = (const float*)d_in[0];
    const float* ln1_g  = (const float*)d_in[1];
    const float* ln1_b  = (const float*)d_in[2];
    const float* qkv_w  = (const float*)d_in[3];
    const float* qkv_b  = (const float*)d_in[4];
    const float* ln2_g  = (const float*)d_in[5];
    const float* ln2_b  = (const float*)d_in[6];
    const float* fc1_w  = (const float*)d_in[7];
    const float* fc1_b  = (const float*)d_in[8];
    const float* mlp_g  = (const float*)d_in[9];
    const float* mlp_b  = (const float*)d_in[10];
    const float* fc2_w  = (const float*)d_in[11];
    const float* fc2_b  = (const float*)d_in[12];
    float* out = (float*)d_out;

    char* ws = (char*)d_ws;
    bf16* qkv_wt  = (bf16*)ws;   ws += (size_t)768 * 256 * 2;
    bf16* fc1_wt  = (bf16*)ws;   ws += (size_t)1024 * 256 * 2;
    bf16* fc2_wt  = (bf16*)ws;   ws += (size_t)256 * 1024 * 2;
    float* c1     = (float*)ws;  ws += 256 * 4;
    float* c2     = (float*)ws;  ws += 256 * 4;
    float* stats3 = (float*)ws;  ws += (size_t)MROWS * 8;
    bf16* xn      = (bf16*)ws;   ws += (size_t)MROWS * CDIM * 2;   // reused as x1n
    bf16* qkvb    = (bf16*)ws;                                      // union with hbuf
    bf16* hbuf    = (bf16*)ws;
    float* x1 = out;

    wt_kernel<<<768,  256, 0, stream>>>(qkv_w, qkv_wt, 256, 768);
    wt_kernel<<<1024, 256, 0, stream>>>(fc1_w, fc1_wt, 256, 1024);
    wt_fold_kernel<<<64, 256, 0, stream>>>(fc2_w, mlp_g, mlp_b, fc2_b, fc2_wt, c1, c2);
    hipMemsetAsync(stats3, 0, (size_t)MROWS * 8, stream);

    ln_apply_f32_kernel<<<MROWS / 4, 256, 0, stream>>>(x, ln1_g, ln1_b, xn);
    gemm_bt_kernel<0><<<dim3(768 / 128, MROWS / 128), 256, 0, stream>>>(
        xn, qkv_wt, qkv_b, nullptr, nullptr, nullptr, nullptr, nullptr, qkvb, 768, 256);
    attn_kernel<<<BATCH * 64 * 2, 256, 0, stream>>>(qkvb, x, x1);
    ln_apply_f32_kernel<<<MROWS / 4, 256, 0, stream>>>(x1, ln2_g, ln2_b, xn);
    gemm_bt_kernel<1><<<dim3(HIDD / 128, MROWS / 128), 256, 0, stream>>>(
        xn, fc1_wt, fc1_b, nullptr, nullptr, nullptr, nullptr, stats3, hbuf, HIDD, 256);
    finalize_stats_kernel<<<MROWS / 256, 256, 0, stream>>>((float2*)stats3);
    gemm_bt_kernel<2><<<dim3(CDIM / 128, MROWS / 128), 256, 0, stream>>>(
        hbuf, fc2_wt, nullptr, x1, c1, c2, (const float2*)stats3, nullptr, out, CDIM, 1024);
}